// Round 5
// baseline (378.913 us; speedup 1.0000x reference)
//
#include <hip/hip_runtime.h>

#define B 256
#define R 2048
#define H 64
#define E 20
#define LN_EPS 1e-5f

#define NB_EDGE 256          // first NB_EDGE main blocks also run the edge path
#define NB_MAIN 1024         // grid size == exactly 4 blocks/CU * 256 CUs
#define TILES_PER_BLOCK 8    // NB_MAIN * TILES_PER_BLOCK * 64 == B*R

typedef float f32x4 __attribute__((ext_vector_type(4)));
typedef short s16x8 __attribute__((ext_vector_type(8)));

__device__ __forceinline__ unsigned short f2bf(float x){
  unsigned int u = __float_as_uint(x);
  u += 0x7fffu + ((u >> 16) & 1u);   // round-to-nearest-even
  return (unsigned short)(u >> 16);
}

__device__ __forceinline__ float wave64_sum(float v){
  #pragma unroll
  for (int m = 1; m < 64; m <<= 1) v += __shfl_xor(v, m, 64);
  return v;
}

// ---------------------------------------------------------------------------
// LDS layouts (union: edge phase vs main phase)
// ---------------------------------------------------------------------------
struct MainS {
  unsigned short lw1[H*72];        // W1_top transposed [n][k], bf16, pad 72
  unsigned short lw2[H*72];        // W2 transposed    [n][k], bf16, pad 72
  unsigned short lhid[4][16*72];   // per-wave hidden tile (bf16)
  float lc1[H];                    // prompt_zero @ W1_bot + fus_b1
  float lb2[H];
  float lgw[H];                    // gate_W top half
  float lgz;                       // prompt_zero . gate_W_bot + gate_b
};
struct EdgeS {
  float wsum[H*H];                 // msg_W top + bottom halves
  float msgbuf[E][H];
  int   et[E];
};
union SMem { MainS m; EdgeS e; };

// ---------------------------------------------------------------------------
// fused kernel: 1024 blocks, all run the dense main path (8 tiles each);
// blocks [0, NB_EDGE) additionally run the per-sample prompt encoder first.
// ---------------------------------------------------------------------------
__global__ __launch_bounds__(256) void fused_kernel(
    const int* __restrict__ qrel, const int* __restrict__ etype,
    const float* __restrict__ base, const float* __restrict__ noise,
    const float* __restrict__ msg_W, const float* __restrict__ msg_b,
    const float* __restrict__ upd_W, const float* __restrict__ upd_b,
    const float* __restrict__ ln_g,  const float* __restrict__ ln_b,
    const float* __restrict__ fus_W1,const float* __restrict__ fus_b1,
    const float* __restrict__ fus_W2,const float* __restrict__ fus_b2,
    const float* __restrict__ gate_W,const float* __restrict__ gate_b,
    int* __restrict__ trows, float* __restrict__ tprompt,
    float* __restrict__ out)
{
  __shared__ SMem smem;
  int tid = threadIdx.x;
  int w = tid >> 6, ln = tid & 63;

  if (blockIdx.x < NB_EDGE) {
    // ------------------------------ EDGE PHASE -----------------------------
    EdgeS* S = &smem.e;
    int b = blockIdx.x;
    if (tid < E) S->et[tid] = etype[b*E + tid];
    for (int i = tid; i < H*H; i += 256)
      S->wsum[i] = msg_W[i] + msg_W[H*H + i];
    __syncthreads();
    int q = qrel[b];

    // phase B: messages (wave w handles e = w, w+4, ...)
    #pragma unroll
    for (int i = 0; i < E/4; ++i) {
      int e = w + i*4;
      int r = S->et[e];
      float hv = (r == q) ? 1.0f : noise[((size_t)b*R + r)*H + ln] * 0.1f;
      float acc = msg_b[ln];
      #pragma unroll 8
      for (int k = 0; k < H; ++k)
        acc += __shfl(hv, k, 64) * S->wsum[k*H + ln];
      S->msgbuf[e][ln] = fmaxf(acc, 0.f);
    }
    __syncthreads();

    // phase C: dedup + aggregate + update-net + LN
    #pragma unroll
    for (int i = 0; i < E/4; ++i) {
      int e = w + i*4;
      int r = S->et[e];
      bool first = true;
      for (int e2 = 0; e2 < e; ++e2) if (S->et[e2] == r) first = false;
      if (!first) { if (ln == 0) trows[b*E + e] = -1; continue; }
      float agg = 0.f;
      for (int e2 = e; e2 < E; ++e2)
        if (S->et[e2] == r) agg += S->msgbuf[e2][ln];
      float u = upd_b[ln];
      #pragma unroll 8
      for (int k = 0; k < H; ++k)
        u += __shfl(agg, k, 64) * upd_W[k*H + ln];
      float mu = wave64_sum(u) * (1.0f/H);
      float d  = u - mu;
      float var= wave64_sum(d*d) * (1.0f/H);
      float p  = d * rsqrtf(var + LN_EPS) * ln_g[ln] + ln_b[ln];
      tprompt[(b*E + e)*H + ln] = p;
      if (ln == 0) trows[b*E + e] = r;
    }
    __syncthreads();   // done with EdgeS; fall through to main phase
  }

  // ------------------------------- MAIN PHASE ------------------------------
  MainS* S = &smem.m;
  // stage: coalesced global read, transposed bf16 LDS write
  for (int i = tid; i < H*H; i += 256) {
    int k = i >> 6, n = i & 63;
    S->lw1[n*72 + k] = f2bf(fus_W1[i]);   // top half of fus_W1
    S->lw2[n*72 + k] = f2bf(fus_W2[i]);
  }
  if (tid < H) {
    S->lb2[tid] = fus_b2[tid];
    S->lgw[tid] = gate_W[tid];
  }
  if (tid < 64 && w == 0) {  // wave 0: prompt_zero, c1z, gz
    float u  = upd_b[tid];
    float mu = wave64_sum(u) * (1.0f/H);
    float d  = u - mu;
    float var= wave64_sum(d*d) * (1.0f/H);
    float p  = d * rsqrtf(var + LN_EPS) * ln_g[tid] + ln_b[tid];
    float acc = fus_b1[tid];
    #pragma unroll 8
    for (int k = 0; k < H; ++k)
      acc += __shfl(p, k, 64) * fus_W1[(H+k)*H + tid];
    S->lc1[tid] = acc;
    float gp = p * gate_W[H + tid];
    gp = wave64_sum(gp);
    if (tid == 0) S->lgz = gp + gate_b[0];
  }
  __syncthreads();

  int m = ln & 15, q = ln >> 4;
  float gz = S->lgz;
  int mb = blockIdx.x;

  // prefetch tile 0
  f32x4 a0, a1, a2, a3;
  {
    int rowbase = (mb*TILES_PER_BLOCK)*64 + w*16;
    const float* arow = base + (size_t)(rowbase + m)*H;
    a0 = *(const f32x4*)(arow + q*8);
    a1 = *(const f32x4*)(arow + q*8 + 4);
    a2 = *(const f32x4*)(arow + 32 + q*8);
    a3 = *(const f32x4*)(arow + 32 + q*8 + 4);
  }

  for (int it = 0; it < TILES_PER_BLOCK; ++it) {
    int rowbase = (mb*TILES_PER_BLOCK + it)*64 + w*16;

    // prefetch next tile's A rows (independent; hides load latency)
    f32x4 n0, n1, n2, n3;
    if (it + 1 < TILES_PER_BLOCK) {
      const float* nrow = base + (size_t)(rowbase + 64 + m)*H;
      n0 = *(const f32x4*)(nrow + q*8);
      n1 = *(const f32x4*)(nrow + q*8 + 4);
      n2 = *(const f32x4*)(nrow + 32 + q*8);
      n3 = *(const f32x4*)(nrow + 32 + q*8 + 4);
    }

    // gate logit: base . gate_W_top (reduce across q groups)
    // after the two xor-reduces ALL lanes hold the full row-m dot product.
    float gp = 0.f;
    #pragma unroll
    for (int j = 0; j < 4; ++j) {
      gp += a0[j]*S->lgw[q*8+j]    + a1[j]*S->lgw[q*8+4+j];
      gp += a2[j]*S->lgw[32+q*8+j] + a3[j]*S->lgw[32+q*8+4+j];
    }
    gp += __shfl_xor(gp, 16, 64);
    gp += __shfl_xor(gp, 32, 64);
    float g = 1.0f / (1.0f + __expf(-(gp + gz)));   // gate for row m, in-register

    // A fragments (lane: row m, k = q*8+j)
    s16x8 A0, A1;
    #pragma unroll
    for (int j = 0; j < 4; ++j) {
      A0[j]   = (short)f2bf(a0[j]);
      A0[j+4] = (short)f2bf(a1[j]);
      A1[j]   = (short)f2bf(a2[j]);
      A1[j+4] = (short)f2bf(a3[j]);
    }

    // hidden = relu(base @ W1_top + c1z)   (c1z folded into C-init)
    f32x4 hacc[4];
    #pragma unroll
    for (int ct = 0; ct < 4; ++ct) {
      const s16x8 B0 = *(const s16x8*)&S->lw1[(ct*16 + m)*72 + q*8];
      const s16x8 B1 = *(const s16x8*)&S->lw1[(ct*16 + m)*72 + 32 + q*8];
      float c1v = S->lc1[ct*16 + m];
      f32x4 c = {c1v, c1v, c1v, c1v};
      c = __builtin_amdgcn_mfma_f32_16x16x32_bf16(A0, B0, c, 0, 0, 0);
      hacc[ct] = __builtin_amdgcn_mfma_f32_16x16x32_bf16(A1, B1, c, 0, 0, 0);
    }
    // D layout: col = ct*16+m, row = q*4+r  -> per-wave LDS round trip
    #pragma unroll
    for (int ct = 0; ct < 4; ++ct) {
      #pragma unroll
      for (int r = 0; r < 4; ++r) {
        float v = fmaxf(hacc[ct][r], 0.f);
        S->lhid[w][(q*4 + r)*72 + ct*16 + m] = f2bf(v);
      }
    }
    // same-wave write->read: compiler inserts lgkmcnt wait; no __syncthreads
    s16x8 HA0 = *(const s16x8*)&S->lhid[w][m*72 + q*8];
    s16x8 HA1 = *(const s16x8*)&S->lhid[w][m*72 + 32 + q*8];

    // fused^T = W2^T @ hidden^T  (operand swap):
    //   A' = W2^T fragment == our existing lw2 B-read
    //   B' = hidden^T fragment == our existing HA read
    //   D' lane (m,q), tile ct, reg j = F[row m][col ct*16 + q*4 + j]
    //   C-init = fus_b2[ct*16 + q*4 .. +3]  (vector LDS read)
    const float* brow = base + (size_t)(rowbase + m)*H;
    float*       orow = out  + (size_t)(rowbase + m)*H;
    #pragma unroll
    for (int ct = 0; ct < 4; ++ct) {
      const s16x8 B0 = *(const s16x8*)&S->lw2[(ct*16 + m)*72 + q*8];
      const s16x8 B1 = *(const s16x8*)&S->lw2[(ct*16 + m)*72 + 32 + q*8];
      f32x4 c = *(const f32x4*)&S->lb2[ct*16 + q*4];
      c = __builtin_amdgcn_mfma_f32_16x16x32_bf16(B0, HA0, c, 0, 0, 0);
      f32x4 facc = __builtin_amdgcn_mfma_f32_16x16x32_bf16(B1, HA1, c, 0, 0, 0);

      int col = ct*16 + q*4;
      f32x4 bv = *(const f32x4*)(brow + col);
      f32x4 o;
      #pragma unroll
      for (int j = 0; j < 4; ++j)
        o[j] = fmaf(g, facc[j] - bv[j], bv[j]);
      *(f32x4*)(orow + col) = o;
    }

    a0 = n0; a1 = n1; a2 = n2; a3 = n3;
  }
}

// ---------------------------------------------------------------------------
// fixup: overwrite the <=E touched rows per sample with their true prompt.
// Wave w handles edges w, w+4, ... ; weights staged in LDS; no barriers after.
// ---------------------------------------------------------------------------
__global__ __launch_bounds__(256) void fixup_kernel(
    const float* __restrict__ base,
    const float* __restrict__ fus_W1, const float* __restrict__ fus_b1,
    const float* __restrict__ fus_W2, const float* __restrict__ fus_b2,
    const float* __restrict__ gate_W, const float* __restrict__ gate_b,
    const int* __restrict__ trows, const float* __restrict__ tprompt,
    float* __restrict__ out)
{
  __shared__ float W1s[2*H*H];   // 32 KB
  __shared__ float W2s[H*H];     // 16 KB
  int b = blockIdx.x, tid = threadIdx.x, w = tid >> 6, ln = tid & 63;
  for (int i = tid; i < 2*H*H; i += 256) W1s[i] = fus_W1[i];
  for (int i = tid; i < H*H;   i += 256) W2s[i] = fus_W2[i];
  __syncthreads();
  float gb = gate_b[0];
  #pragma unroll
  for (int i = 0; i < E/4; ++i) {
    int e = w + i*4;
    int r = trows[b*E + e];
    if (r < 0) continue;
    float bv = base[((size_t)b*R + r)*H + ln];
    float pv = tprompt[(b*E + e)*H + ln];
    float acc = fus_b1[ln];
    #pragma unroll 8
    for (int k = 0; k < H; ++k)
      acc += __shfl(bv, k, 64)*W1s[k*H + ln] + __shfl(pv, k, 64)*W1s[(H+k)*H + ln];
    float h = fmaxf(acc, 0.f);
    float f = fus_b2[ln];
    #pragma unroll 8
    for (int k = 0; k < H; ++k)
      f += __shfl(h, k, 64)*W2s[k*H + ln];
    float gp = bv*gate_W[ln] + pv*gate_W[H + ln];
    gp = wave64_sum(gp);
    float g = 1.0f/(1.0f + __expf(-(gp + gb)));
    out[((size_t)b*R + r)*H + ln] = fmaf(g, f - bv, bv);
  }
}

// ---------------------------------------------------------------------------
extern "C" void kernel_launch(void* const* d_in, const int* in_sizes, int n_in,
                              void* d_out, int out_size, void* d_ws, size_t ws_size,
                              hipStream_t stream)
{
  const int*   qrel   = (const int*)d_in[0];
  const int*   etyp   = (const int*)d_in[1];
  const float* base   = (const float*)d_in[2];
  const float* noise  = (const float*)d_in[3];
  const float* msg_W  = (const float*)d_in[4];
  const float* msg_b  = (const float*)d_in[5];
  const float* upd_W  = (const float*)d_in[6];
  const float* upd_b  = (const float*)d_in[7];
  const float* ln_g   = (const float*)d_in[8];
  const float* ln_b   = (const float*)d_in[9];
  const float* fus_W1 = (const float*)d_in[10];
  const float* fus_b1 = (const float*)d_in[11];
  const float* fus_W2 = (const float*)d_in[12];
  const float* fus_b2 = (const float*)d_in[13];
  const float* gate_W = (const float*)d_in[14];
  const float* gate_b = (const float*)d_in[15];
  float* out = (float*)d_out;

  char* ws = (char*)d_ws;
  float* tprompt = (float*)ws;                       // B*E*H f32
  int*   trows   = (int*)(ws + (size_t)B*E*H*4);     // B*E int

  fused_kernel<<<NB_MAIN, 256, 0, stream>>>(
      qrel, etyp, base, noise, msg_W, msg_b, upd_W, upd_b, ln_g, ln_b,
      fus_W1, fus_b1, fus_W2, fus_b2, gate_W, gate_b,
      trows, tprompt, out);
  fixup_kernel<<<B, 256, 0, stream>>>(base, fus_W1, fus_b1, fus_W2, fus_b2,
                                      gate_W, gate_b, trows, tprompt, out);
}

// Round 6
// 358.026 us; speedup vs baseline: 1.0583x; 1.0583x over previous
//
#include <hip/hip_runtime.h>

#define B 256
#define R 2048
#define H 64
#define E 20
#define LN_EPS 1e-5f

#define NB_EDGE 256          // first NB_EDGE main blocks also run the edge path
#define NB_MAIN 1024         // grid size == exactly 4 blocks/CU * 256 CUs
#define TILES_PER_BLOCK 8    // NB_MAIN * TILES_PER_BLOCK * 64 == B*R

typedef float f32x4 __attribute__((ext_vector_type(4)));
typedef short s16x8 __attribute__((ext_vector_type(8)));

__device__ __forceinline__ unsigned short f2bf(float x){
  unsigned int u = __float_as_uint(x);
  u += 0x7fffu + ((u >> 16) & 1u);   // round-to-nearest-even
  return (unsigned short)(u >> 16);
}

__device__ __forceinline__ float wave64_sum(float v){
  #pragma unroll
  for (int m = 1; m < 64; m <<= 1) v += __shfl_xor(v, m, 64);
  return v;
}

// ---------------------------------------------------------------------------
// LDS layouts (union: edge phase vs main phase)
// ---------------------------------------------------------------------------
struct MainS {
  unsigned short lw1[H*72];        // W1_top transposed [n][k], bf16, pad 72
  unsigned short lw2[H*72];        // W2 transposed    [n][k], bf16, pad 72
  unsigned short lhid[4][16*72];   // per-wave hidden tile (bf16)
  float lc1[H];                    // prompt_zero @ W1_bot + fus_b1
  float lb2[H];
  float lgw[H];                    // gate_W top half
  float lgz;                       // prompt_zero . gate_W_bot + gate_b
};
struct EdgeS {
  float wsum[H*H];                 // msg_W top + bottom halves
  float msgbuf[E][H];
  int   et[E];
};
union SMem { MainS m; EdgeS e; };

// ---------------------------------------------------------------------------
// fused kernel: 1024 blocks, all run the dense main path (8 tiles each);
// blocks [0, NB_EDGE) additionally run the per-sample prompt encoder first.
// ---------------------------------------------------------------------------
__global__ __launch_bounds__(256) void fused_kernel(
    const int* __restrict__ qrel, const int* __restrict__ etype,
    const float* __restrict__ base, const float* __restrict__ noise,
    const float* __restrict__ msg_W, const float* __restrict__ msg_b,
    const float* __restrict__ upd_W, const float* __restrict__ upd_b,
    const float* __restrict__ ln_g,  const float* __restrict__ ln_b,
    const float* __restrict__ fus_W1,const float* __restrict__ fus_b1,
    const float* __restrict__ fus_W2,const float* __restrict__ fus_b2,
    const float* __restrict__ gate_W,const float* __restrict__ gate_b,
    int* __restrict__ trows, float* __restrict__ tprompt,
    float* __restrict__ out)
{
  __shared__ SMem smem;
  int tid = threadIdx.x;
  int w = tid >> 6, ln = tid & 63;

  if (blockIdx.x < NB_EDGE) {
    // ------------------------------ EDGE PHASE -----------------------------
    EdgeS* S = &smem.e;
    int b = blockIdx.x;
    if (tid < E) S->et[tid] = etype[b*E + tid];
    for (int i = tid; i < H*H; i += 256)
      S->wsum[i] = msg_W[i] + msg_W[H*H + i];
    __syncthreads();
    int q = qrel[b];

    // phase B: messages (wave w handles e = w, w+4, ...)
    #pragma unroll
    for (int i = 0; i < E/4; ++i) {
      int e = w + i*4;
      int r = S->et[e];
      float hv = (r == q) ? 1.0f : noise[((size_t)b*R + r)*H + ln] * 0.1f;
      float acc = msg_b[ln];
      #pragma unroll 8
      for (int k = 0; k < H; ++k)
        acc += __shfl(hv, k, 64) * S->wsum[k*H + ln];
      S->msgbuf[e][ln] = fmaxf(acc, 0.f);
    }
    __syncthreads();

    // phase C: dedup + aggregate + update-net + LN
    #pragma unroll
    for (int i = 0; i < E/4; ++i) {
      int e = w + i*4;
      int r = S->et[e];
      bool first = true;
      for (int e2 = 0; e2 < e; ++e2) if (S->et[e2] == r) first = false;
      if (!first) { if (ln == 0) trows[b*E + e] = -1; continue; }
      float agg = 0.f;
      for (int e2 = e; e2 < E; ++e2)
        if (S->et[e2] == r) agg += S->msgbuf[e2][ln];
      float u = upd_b[ln];
      #pragma unroll 8
      for (int k = 0; k < H; ++k)
        u += __shfl(agg, k, 64) * upd_W[k*H + ln];
      float mu = wave64_sum(u) * (1.0f/H);
      float d  = u - mu;
      float var= wave64_sum(d*d) * (1.0f/H);
      float p  = d * rsqrtf(var + LN_EPS) * ln_g[ln] + ln_b[ln];
      tprompt[(b*E + e)*H + ln] = p;
      if (ln == 0) trows[b*E + e] = r;
    }
    __syncthreads();   // done with EdgeS; fall through to main phase
  }

  // ------------------------------- MAIN PHASE ------------------------------
  MainS* S = &smem.m;
  // stage: coalesced global read, transposed bf16 LDS write
  for (int i = tid; i < H*H; i += 256) {
    int k = i >> 6, n = i & 63;
    S->lw1[n*72 + k] = f2bf(fus_W1[i]);   // top half of fus_W1
    S->lw2[n*72 + k] = f2bf(fus_W2[i]);
  }
  if (tid < H) {
    S->lb2[tid] = fus_b2[tid];
    S->lgw[tid] = gate_W[tid];
  }
  if (tid < 64 && w == 0) {  // wave 0: prompt_zero, c1z, gz
    float u  = upd_b[tid];
    float mu = wave64_sum(u) * (1.0f/H);
    float d  = u - mu;
    float var= wave64_sum(d*d) * (1.0f/H);
    float p  = d * rsqrtf(var + LN_EPS) * ln_g[tid] + ln_b[tid];
    float acc = fus_b1[tid];
    #pragma unroll 8
    for (int k = 0; k < H; ++k)
      acc += __shfl(p, k, 64) * fus_W1[(H+k)*H + tid];
    S->lc1[tid] = acc;
    float gp = p * gate_W[H + tid];
    gp = wave64_sum(gp);
    if (tid == 0) S->lgz = gp + gate_b[0];
  }
  __syncthreads();

  int m = ln & 15, q = ln >> 4;
  float gz = S->lgz;
  int mb = blockIdx.x;

  // ---- hoist loop-invariant weight fragments into registers (64 VGPRs) ----
  // This removes 16 conflicted ds_read_b128 per tile (the dominant
  // SQ_LDS_BANK_CONFLICT source: start bank = 4*(m+q) mod 32 -> 8-way).
  s16x8 W1F0[4], W1F1[4], W2F0[4], W2F1[4];
  #pragma unroll
  for (int ct = 0; ct < 4; ++ct) {
    W1F0[ct] = *(const s16x8*)&S->lw1[(ct*16 + m)*72 + q*8];
    W1F1[ct] = *(const s16x8*)&S->lw1[(ct*16 + m)*72 + 32 + q*8];
    W2F0[ct] = *(const s16x8*)&S->lw2[(ct*16 + m)*72 + q*8];
    W2F1[ct] = *(const s16x8*)&S->lw2[(ct*16 + m)*72 + 32 + q*8];
  }

  // prefetch tile 0
  f32x4 a0, a1, a2, a3;
  {
    int rowbase = (mb*TILES_PER_BLOCK)*64 + w*16;
    const float* arow = base + (size_t)(rowbase + m)*H;
    a0 = *(const f32x4*)(arow + q*8);
    a1 = *(const f32x4*)(arow + q*8 + 4);
    a2 = *(const f32x4*)(arow + 32 + q*8);
    a3 = *(const f32x4*)(arow + 32 + q*8 + 4);
  }

  for (int it = 0; it < TILES_PER_BLOCK; ++it) {
    int rowbase = (mb*TILES_PER_BLOCK + it)*64 + w*16;

    // prefetch next tile's A rows (independent; hides load latency)
    f32x4 n0, n1, n2, n3;
    if (it + 1 < TILES_PER_BLOCK) {
      const float* nrow = base + (size_t)(rowbase + 64 + m)*H;
      n0 = *(const f32x4*)(nrow + q*8);
      n1 = *(const f32x4*)(nrow + q*8 + 4);
      n2 = *(const f32x4*)(nrow + 32 + q*8);
      n3 = *(const f32x4*)(nrow + 32 + q*8 + 4);
    }

    // gate logit: base . gate_W_top (vector LDS reads; reduce across q groups)
    f32x4 gw0 = *(const f32x4*)&S->lgw[q*8];
    f32x4 gw1 = *(const f32x4*)&S->lgw[q*8 + 4];
    f32x4 gw2 = *(const f32x4*)&S->lgw[32 + q*8];
    f32x4 gw3 = *(const f32x4*)&S->lgw[32 + q*8 + 4];
    float gp = 0.f;
    #pragma unroll
    for (int j = 0; j < 4; ++j) {
      gp += a0[j]*gw0[j] + a1[j]*gw1[j];
      gp += a2[j]*gw2[j] + a3[j]*gw3[j];
    }
    gp += __shfl_xor(gp, 16, 64);
    gp += __shfl_xor(gp, 32, 64);
    float g = 1.0f / (1.0f + __expf(-(gp + gz)));   // gate for row m, in-register

    // A fragments (lane: row m, k = q*8+j)
    s16x8 A0, A1;
    #pragma unroll
    for (int j = 0; j < 4; ++j) {
      A0[j]   = (short)f2bf(a0[j]);
      A0[j+4] = (short)f2bf(a1[j]);
      A1[j]   = (short)f2bf(a2[j]);
      A1[j+4] = (short)f2bf(a3[j]);
    }

    // hidden = relu(base @ W1_top + c1z)   (c1z folded into C-init)
    f32x4 hacc[4];
    #pragma unroll
    for (int ct = 0; ct < 4; ++ct) {
      float c1v = S->lc1[ct*16 + m];
      f32x4 c = {c1v, c1v, c1v, c1v};
      c = __builtin_amdgcn_mfma_f32_16x16x32_bf16(A0, W1F0[ct], c, 0, 0, 0);
      hacc[ct] = __builtin_amdgcn_mfma_f32_16x16x32_bf16(A1, W1F1[ct], c, 0, 0, 0);
    }
    // D layout: col = ct*16+m, row = q*4+r  -> per-wave LDS round trip
    #pragma unroll
    for (int ct = 0; ct < 4; ++ct) {
      #pragma unroll
      for (int r = 0; r < 4; ++r) {
        float v = fmaxf(hacc[ct][r], 0.f);
        S->lhid[w][(q*4 + r)*72 + ct*16 + m] = f2bf(v);
      }
    }
    // same-wave write->read: compiler inserts lgkmcnt wait; no __syncthreads
    s16x8 HA0 = *(const s16x8*)&S->lhid[w][m*72 + q*8];
    s16x8 HA1 = *(const s16x8*)&S->lhid[w][m*72 + 32 + q*8];

    // fused^T = W2^T @ hidden^T  (operand swap):
    //   A' = W2^T fragment == register W2F
    //   B' = hidden^T fragment == HA read
    //   D' lane (m,q), tile ct, reg j = F[row m][col ct*16 + q*4 + j]
    //   C-init = fus_b2[ct*16 + q*4 .. +3]  (vector LDS read)
    const float* brow = base + (size_t)(rowbase + m)*H;
    float*       orow = out  + (size_t)(rowbase + m)*H;
    #pragma unroll
    for (int ct = 0; ct < 4; ++ct) {
      f32x4 c = *(const f32x4*)&S->lb2[ct*16 + q*4];
      c = __builtin_amdgcn_mfma_f32_16x16x32_bf16(W2F0[ct], HA0, c, 0, 0, 0);
      f32x4 facc = __builtin_amdgcn_mfma_f32_16x16x32_bf16(W2F1[ct], HA1, c, 0, 0, 0);

      int col = ct*16 + q*4;
      f32x4 bv = *(const f32x4*)(brow + col);
      f32x4 o;
      #pragma unroll
      for (int j = 0; j < 4; ++j)
        o[j] = fmaf(g, facc[j] - bv[j], bv[j]);
      *(f32x4*)(orow + col) = o;
    }

    a0 = n0; a1 = n1; a2 = n2; a3 = n3;
  }
}

// ---------------------------------------------------------------------------
// fixup: overwrite the <=E touched rows per sample with their true prompt.
// Wave w handles edges w, w+4, ... ; weights staged in LDS; no barriers after.
// ---------------------------------------------------------------------------
__global__ __launch_bounds__(256) void fixup_kernel(
    const float* __restrict__ base,
    const float* __restrict__ fus_W1, const float* __restrict__ fus_b1,
    const float* __restrict__ fus_W2, const float* __restrict__ fus_b2,
    const float* __restrict__ gate_W, const float* __restrict__ gate_b,
    const int* __restrict__ trows, const float* __restrict__ tprompt,
    float* __restrict__ out)
{
  __shared__ float W1s[2*H*H];   // 32 KB
  __shared__ float W2s[H*H];     // 16 KB
  int b = blockIdx.x, tid = threadIdx.x, w = tid >> 6, ln = tid & 63;
  for (int i = tid; i < 2*H*H; i += 256) W1s[i] = fus_W1[i];
  for (int i = tid; i < H*H;   i += 256) W2s[i] = fus_W2[i];
  __syncthreads();
  float gb = gate_b[0];
  #pragma unroll
  for (int i = 0; i < E/4; ++i) {
    int e = w + i*4;
    int r = trows[b*E + e];
    if (r < 0) continue;
    float bv = base[((size_t)b*R + r)*H + ln];
    float pv = tprompt[(b*E + e)*H + ln];
    float acc = fus_b1[ln];
    #pragma unroll 8
    for (int k = 0; k < H; ++k)
      acc += __shfl(bv, k, 64)*W1s[k*H + ln] + __shfl(pv, k, 64)*W1s[(H+k)*H + ln];
    float h = fmaxf(acc, 0.f);
    float f = fus_b2[ln];
    #pragma unroll 8
    for (int k = 0; k < H; ++k)
      f += __shfl(h, k, 64)*W2s[k*H + ln];
    float gp = bv*gate_W[ln] + pv*gate_W[H + ln];
    gp = wave64_sum(gp);
    float g = 1.0f/(1.0f + __expf(-(gp + gb)));
    out[((size_t)b*R + r)*H + ln] = fmaf(g, f - bv, bv);
  }
}

// ---------------------------------------------------------------------------
extern "C" void kernel_launch(void* const* d_in, const int* in_sizes, int n_in,
                              void* d_out, int out_size, void* d_ws, size_t ws_size,
                              hipStream_t stream)
{
  const int*   qrel   = (const int*)d_in[0];
  const int*   etyp   = (const int*)d_in[1];
  const float* base   = (const float*)d_in[2];
  const float* noise  = (const float*)d_in[3];
  const float* msg_W  = (const float*)d_in[4];
  const float* msg_b  = (const float*)d_in[5];
  const float* upd_W  = (const float*)d_in[6];
  const float* upd_b  = (const float*)d_in[7];
  const float* ln_g   = (const float*)d_in[8];
  const float* ln_b   = (const float*)d_in[9];
  const float* fus_W1 = (const float*)d_in[10];
  const float* fus_b1 = (const float*)d_in[11];
  const float* fus_W2 = (const float*)d_in[12];
  const float* fus_b2 = (const float*)d_in[13];
  const float* gate_W = (const float*)d_in[14];
  const float* gate_b = (const float*)d_in[15];
  float* out = (float*)d_out;

  char* ws = (char*)d_ws;
  float* tprompt = (float*)ws;                       // B*E*H f32
  int*   trows   = (int*)(ws + (size_t)B*E*H*4);     // B*E int

  fused_kernel<<<NB_MAIN, 256, 0, stream>>>(
      qrel, etyp, base, noise, msg_W, msg_b, upd_W, upd_b, ln_g, ln_b,
      fus_W1, fus_b1, fus_W2, fus_b2, gate_W, gate_b,
      trows, tprompt, out);
  fixup_kernel<<<B, 256, 0, stream>>>(base, fus_W1, fus_b1, fus_W2, fus_b2,
                                      gate_W, gate_b, trows, tprompt, out);
}